// Round 12
// baseline (68.457 us; speedup 1.0000x reference)
//
#include <hip/hip_runtime.h>
#include <float.h>

// RoIPool (torch semantics: round(coords*scale), clamp, AdaptiveMaxPool2d bins)
// features: [B=4, C=128, H=64, W=64] fp32; rois: [N,5]; out: [N,128,7,7] fp32
//
// Block = (ROI, 16-channel slab): float4-stage crop into LDS, pool 49x16.
// R12 change: stage only the NEEDED segments sa..se of each (row,ch) span
// (sa=(x1-xa)/4, se=(x2-xa)/4). R11 staged all 5 -> ~30-35% of global volume
// was beyond x2 / before x1, never read by the pool. Pure VMEM-request cut;
// skipped LDS slots hold garbage but are provably unaddressed by the pool.
//
// Bin window is 4x4: adaptive bin size = ceil((i+1)h/P)-floor(ih/P) <= h/P+2
// <= 4 for h<=17 (R4/R6's absmax-3.69 bug was assuming 3).
// LDS row stride 81 f4 (324 fl): bank rotates with y (R11; neutral but free).

#define POOL_P 7
#define NBINS  49
#define SPATIAL_SCALE 0.0625f
#define SLAB   16                   // channels per block (C/SLAB = 8 slabs)
#define MAXH   17                   // max crop rows in LDS tile
#define MAXW   20                   // col span: min(x1&~3, 44) .. +19 covers x1..x2
#define SEGS   (MAXW / 4)           // 5 float4 segments per (row,ch)
#define ROWF4  (SLAB * SEGS + 1)    // 81 f4 per row (pad breaks 320-stride banks)
#define ROWFL  (ROWF4 * 4)          // 324 floats per row

__global__ __launch_bounds__(256) void roipool_kernel(
    const float* __restrict__ feat,
    const float* __restrict__ rois,
    float* __restrict__ out,
    int C, int H, int W, int N)
{
    __shared__ float4 lds4[MAXH * ROWF4];       // 1377 f4 = 22032 B -> 7 blk/CU
    const float* lds = (const float*)lds4;

    const int bid  = blockIdx.x;
    const int slab = bid & 7;
    const int n    = bid >> 3;
    const int tid  = threadIdx.x;

    // ROI decode (block-uniform)
    const float* r = rois + (size_t)n * 5;
    const int b  = (int)r[0];                                  // astype(int32) = trunc
    int x1 = max(__float2int_rn(r[1] * SPATIAL_SCALE), 0);     // jnp.round = half-to-even
    int y1 = max(__float2int_rn(r[2] * SPATIAL_SCALE), 0);
    int x2 = min(__float2int_rn(r[3] * SPATIAL_SCALE), W - 1);
    int y2 = min(__float2int_rn(r[4] * SPATIAL_SCALE), H - 1);

    const int h = y2 - y1 + 1;                  // 1..17 for this generator
    const int w = x2 - x1 + 1;
    const int xa = min(x1 & ~3, W - MAXW);      // aligned; xa+19 <= W-1; x2-xa <= 19

    const size_t HWs = (size_t)H * W;
    const float* fb  = feat + ((size_t)b * C + slab * SLAB) * HWs;

    const bool fast = (h <= MAXH) && (w <= MAXW - 3);

    if (fast) {
        const int sa = (x1 - xa) >> 2;          // first needed segment (0..4)
        const int se = (x2 - xa) >> 2;          // last needed segment (inclusive)
        // stage h*81 f4 slots (slot 80 skipped); only segs sa..se issue loads:
        // lds4[row*81 + ch*5 + seg] = feat[ch][y1+row][xa+seg*4 ..+3]
        const int hf4 = h * ROWF4;
        for (int s = tid; s < hf4; s += 256) {
            const int row = s / ROWF4;          // const divisors only
            const int rem = s - row * ROWF4;
            if (rem < SLAB * SEGS) {
                const int ch  = rem / SEGS;
                const int seg = rem - ch * SEGS;
                if (seg >= sa && seg <= se)
                    lds4[s] = *(const float4*)(fb + (size_t)ch * HWs
                                                  + (size_t)(y1 + row) * W + xa + seg * 4);
            }
        }
    }
    __syncthreads();

    for (int o = tid; o < NBINS * SLAB; o += 256) {
        const int ch  = o / NBINS;
        const int bin = o - ch * NBINS;
        const int px  = bin % POOL_P;
        const int py  = bin / POOL_P;

        // AdaptiveMaxPool2d: start=floor(i*h/P), end=ceil((i+1)*h/P)
        // non-negative operands -> C division == floor; ceil via (a+P-1)/P
        const int ys = y1 + (py * h) / POOL_P;
        const int ye = y1 + ((py + 1) * h + POOL_P - 1) / POOL_P;
        const int xs = x1 + (px * w) / POOL_P;
        const int xe = x1 + ((px + 1) * w + POOL_P - 1) / POOL_P;
        const int ny = ye - ys;                 // 1..4 when h<=17
        const int nx = xe - xs;

        float m = -FLT_MAX;                     // empty bin -> finfo(f32).min
        if (fast) {
            // lds float index: (y-y1)*324 + ch*20 + (x-xa)
            // reads stay in loaded segs: x1 <= x <= x2 -> 4*sa <= x-xa <= 4*se+3
            const int base = ch * MAXW - y1 * ROWFL - xa;
            if (ny <= 4 && nx <= 4) {
                // 4x4 clamped window: duplicate taps are max-idempotent
                #pragma unroll
                for (int dy = 0; dy < 4; ++dy) {
                    const int y = ys + min(dy, ny - 1);
                    #pragma unroll
                    for (int dx = 0; dx < 4; ++dx) {
                        const int x = xs + min(dx, nx - 1);
                        m = fmaxf(m, lds[base + y * ROWFL + x]);
                    }
                }
            } else {
                // unreachable for h,w<=17, kept for safety
                for (int y = ys; y < ye; ++y)
                    for (int x = xs; x < xe; ++x)
                        m = fmaxf(m, lds[base + y * ROWFL + x]);
            }
        } else {
            // crop too big for LDS tile -> direct global pooling
            const float* f = fb + (size_t)ch * HWs;
            for (int y = ys; y < ye; ++y)
                for (int x = xs; x < xe; ++x)
                    m = fmaxf(m, f[(size_t)y * W + x]);
        }
        out[((size_t)n * C + slab * SLAB + ch) * NBINS + bin] = m;
    }
}

extern "C" void kernel_launch(void* const* d_in, const int* in_sizes, int n_in,
                              void* d_out, int out_size, void* d_ws, size_t ws_size,
                              hipStream_t stream) {
    const float* features = (const float*)d_in[0];   // [B, C, H, W]
    const float* rois     = (const float*)d_in[1];   // [N, 5]
    float* out            = (float*)d_out;           // [N, C, 7, 7]

    const int C = 128, H = 64, W = 64;
    const int N = in_sizes[1] / 5;                   // 256

    const int grid = N * (C / SLAB);                 // 2048
    roipool_kernel<<<grid, 256, 0, stream>>>(features, rois, out, C, H, W, N);
}

// Round 13
// 66.454 us; speedup vs baseline: 1.0301x; 1.0301x over previous
//
#include <hip/hip_runtime.h>
#include <float.h>

// RoIPool (torch semantics: round(coords*scale), clamp, AdaptiveMaxPool2d bins)
// features: [B=4, C=128, H=64, W=64] fp32; rois: [N,5]; out: [N,128,7,7] fp32
//
// Block = (ROI, 16-channel slab): float4-stage needed crop segs into LDS,
// pool 49 bins x 16 ch. R13 change (pool phase only): dynamic tap loops
// (avg bin 1.8x1.8 -> ~3.2 taps vs fixed 4x4=16) + channel-pair CPT=2
// (one bin decode feeds ch0 and ch0+8; tap addr reused, +160 fl = same
// bank 2-way = free). Pool issue count ~ -65%. Staging unchanged (R12).
//
// Adaptive bin size = ceil((i+1)h/P)-floor(ih/P) <= h/P+2 <= 4 for h<=17;
// dynamic loops are correct for ANY size that fits LDS (kills the R4/R6
// fixed-window bug class). LDS row stride 81 f4 / 324 fl (bank-rotating).

#define POOL_P 7
#define NBINS  49
#define SPATIAL_SCALE 0.0625f
#define SLAB   16                   // channels per block (C/SLAB = 8 slabs)
#define MAXH   17                   // max crop rows in LDS tile
#define MAXW   20                   // col span: min(x1&~3, 44) .. +19 covers x1..x2
#define SEGS   (MAXW / 4)           // 5 float4 segments per (row,ch)
#define ROWF4  (SLAB * SEGS + 1)    // 81 f4 per row
#define ROWFL  (ROWF4 * 4)          // 324 floats per row
#define HCH    (SLAB / 2)           // 8: channel-pair stride

__global__ __launch_bounds__(256) void roipool_kernel(
    const float* __restrict__ feat,
    const float* __restrict__ rois,
    float* __restrict__ out,
    int C, int H, int W, int N)
{
    __shared__ float4 lds4[MAXH * ROWF4];       // 1377 f4 = 22032 B -> 7 blk/CU
    const float* lds = (const float*)lds4;

    const int bid  = blockIdx.x;
    const int slab = bid & 7;
    const int n    = bid >> 3;
    const int tid  = threadIdx.x;

    // ROI decode (block-uniform)
    const float* r = rois + (size_t)n * 5;
    const int b  = (int)r[0];                                  // astype(int32) = trunc
    int x1 = max(__float2int_rn(r[1] * SPATIAL_SCALE), 0);     // jnp.round = half-to-even
    int y1 = max(__float2int_rn(r[2] * SPATIAL_SCALE), 0);
    int x2 = min(__float2int_rn(r[3] * SPATIAL_SCALE), W - 1);
    int y2 = min(__float2int_rn(r[4] * SPATIAL_SCALE), H - 1);

    const int h = y2 - y1 + 1;                  // 1..17 for this generator
    const int w = x2 - x1 + 1;
    const int xa = min(x1 & ~3, W - MAXW);      // aligned; xa+19 <= W-1; x2-xa <= 19

    const size_t HWs = (size_t)H * W;
    const float* fb  = feat + ((size_t)b * C + slab * SLAB) * HWs;

    const bool fast = (h <= MAXH) && (w <= MAXW - 3);

    if (fast) {
        const int sa = (x1 - xa) >> 2;          // first needed segment
        const int se = (x2 - xa) >> 2;          // last needed segment (incl)
        const int hf4 = h * ROWF4;
        for (int s = tid; s < hf4; s += 256) {
            const int row = s / ROWF4;          // const divisors only
            const int rem = s - row * ROWF4;
            if (rem < SLAB * SEGS) {
                const int ch  = rem / SEGS;
                const int seg = rem - ch * SEGS;
                if (seg >= sa && seg <= se)
                    lds4[s] = *(const float4*)(fb + (size_t)ch * HWs
                                                  + (size_t)(y1 + row) * W + xa + seg * 4);
            }
        }
    }
    __syncthreads();

    // pool: one iteration = one bin x channel-pair (ch0, ch0+8)
    for (int o = tid; o < NBINS * HCH; o += 256) {
        const int ch0 = o / NBINS;              // 0..7
        const int bin = o - ch0 * NBINS;
        const int px  = bin % POOL_P;
        const int py  = bin / POOL_P;

        // AdaptiveMaxPool2d: start=floor(i*h/P), end=ceil((i+1)*h/P)
        // non-negative operands -> C division == floor; ceil via (a+P-1)/P
        const int ys = y1 + (py * h) / POOL_P;
        const int ye = y1 + ((py + 1) * h + POOL_P - 1) / POOL_P;
        const int xs = x1 + (px * w) / POOL_P;
        const int xe = x1 + ((px + 1) * w + POOL_P - 1) / POOL_P;

        float m0 = -FLT_MAX, m1 = -FLT_MAX;     // empty bin -> finfo(f32).min
        if (fast) {
            // lds float index: (y-y1)*324 + ch*20 + (x-xa)
            const int base = ch0 * MAXW - y1 * ROWFL - xa;
            for (int y = ys; y < ye; ++y) {
                const int rowb = base + y * ROWFL;
                for (int x = xs; x < xe; ++x) {
                    m0 = fmaxf(m0, lds[rowb + x]);
                    m1 = fmaxf(m1, lds[rowb + HCH * MAXW + x]);   // +160: same bank, free
                }
            }
        } else {
            // crop too big for LDS tile -> direct global pooling
            const float* f0 = fb + (size_t)ch0 * HWs;
            const float* f1 = f0 + (size_t)HCH * HWs;
            for (int y = ys; y < ye; ++y)
                for (int x = xs; x < xe; ++x) {
                    m0 = fmaxf(m0, f0[(size_t)y * W + x]);
                    m1 = fmaxf(m1, f1[(size_t)y * W + x]);
                }
        }
        const size_t ob = ((size_t)n * C + slab * SLAB + ch0) * NBINS + bin;
        out[ob] = m0;
        out[ob + (size_t)HCH * NBINS] = m1;
    }
}

extern "C" void kernel_launch(void* const* d_in, const int* in_sizes, int n_in,
                              void* d_out, int out_size, void* d_ws, size_t ws_size,
                              hipStream_t stream) {
    const float* features = (const float*)d_in[0];   // [B, C, H, W]
    const float* rois     = (const float*)d_in[1];   // [N, 5]
    float* out            = (float*)d_out;           // [N, C, 7, 7]

    const int C = 128, H = 64, W = 64;
    const int N = in_sizes[1] / 5;                   // 256

    const int grid = N * (C / SLAB);                 // 2048
    roipool_kernel<<<grid, 256, 0, stream>>>(features, rois, out, C, H, W, N);
}

// Round 14
// 65.848 us; speedup vs baseline: 1.0396x; 1.0092x over previous
//
#include <hip/hip_runtime.h>
#include <float.h>

// RoIPool (torch semantics: round(coords*scale), clamp, AdaptiveMaxPool2d bins)
// features: [B=4, C=128, H=64, W=64] fp32; rois: [N,5]; out: [N,128,7,7] fp32
//
// Block = (ROI, 16-channel slab). R14 change: stage via
// __builtin_amdgcn_global_load_lds (width 16, direct HBM->LDS DMA) -- deletes
// ~850 ds_write_b128 + VGPR round-trip per block; one vmcnt window drained by
// __syncthreads. Wave-uniform-LDS-base rule (m104): NO interior predication --
// pad/trimmed lanes stay ACTIVE loading clamped duplicate addresses (their
// slots are never read); only the loop tail is exec-masked (suffix lanes ->
// lane0 active -> readfirstlane base correct; s contiguous in lane -> each
// active lane L writes base+16L = its own slot).
//
// Pool phase = R13 best: dynamic tap loops (avg 3.2 taps vs 16) + channel-pair.
// Adaptive bin size <= h/P+2 <= 4 for h<=17 (R4/R6 bug was assuming 3).
// LDS row stride 81 f4 / 324 fl (bank-rotating, R11).

#define POOL_P 7
#define NBINS  49
#define SPATIAL_SCALE 0.0625f
#define SLAB   16                   // channels per block (C/SLAB = 8 slabs)
#define MAXH   17                   // max crop rows in LDS tile
#define MAXW   20                   // col span: min(x1&~3, 44) .. +19 covers x1..x2
#define SEGS   (MAXW / 4)           // 5 float4 segments per (row,ch)
#define ROWF4  (SLAB * SEGS + 1)    // 81 f4 per row
#define ROWFL  (ROWF4 * 4)          // 324 floats per row
#define HCH    (SLAB / 2)           // 8: channel-pair stride

__global__ __launch_bounds__(256) void roipool_kernel(
    const float* __restrict__ feat,
    const float* __restrict__ rois,
    float* __restrict__ out,
    int C, int H, int W, int N)
{
    __shared__ float4 lds4[MAXH * ROWF4];       // 1377 f4 = 22032 B -> 7 blk/CU
    const float* lds = (const float*)lds4;

    const int bid  = blockIdx.x;
    const int slab = bid & 7;
    const int n    = bid >> 3;
    const int tid  = threadIdx.x;

    // ROI decode (block-uniform)
    const float* r = rois + (size_t)n * 5;
    const int b  = (int)r[0];                                  // astype(int32) = trunc
    int x1 = max(__float2int_rn(r[1] * SPATIAL_SCALE), 0);     // jnp.round = half-to-even
    int y1 = max(__float2int_rn(r[2] * SPATIAL_SCALE), 0);
    int x2 = min(__float2int_rn(r[3] * SPATIAL_SCALE), W - 1);
    int y2 = min(__float2int_rn(r[4] * SPATIAL_SCALE), H - 1);

    const int h = y2 - y1 + 1;                  // 1..17 for this generator
    const int w = x2 - x1 + 1;
    const int xa = min(x1 & ~3, W - MAXW);      // aligned; xa+19 <= W-1; x2-xa <= 19

    const size_t HWs = (size_t)H * W;
    const float* fb  = feat + ((size_t)b * C + slab * SLAB) * HWs;

    const bool fast = (h <= MAXH) && (w <= MAXW - 3);

    if (fast) {
        const int sa = (x1 - xa) >> 2;          // first needed segment
        const int se = (x2 - xa) >> 2;          // last needed segment (incl)
        const int hf4 = h * ROWF4;
        for (int s = tid; s < hf4; s += 256) {
            const int row  = s / ROWF4;         // const divisors only
            const int rowc = min(row, h - 1);   // masked-tail lanes: valid addr
            int rem = s - row * ROWF4;
            if (rem >= SLAB * SEGS) rem = SLAB * SEGS - 1;   // pad slot -> dup
            int ch  = rem / SEGS;
            int seg = rem - ch * SEGS;
            seg = min(max(seg, sa), se);        // trimmed segs -> dup (never read)
            const float* g = fb + (size_t)ch * HWs
                                + (size_t)(y1 + rowc) * W + xa + seg * 4;
            __builtin_amdgcn_global_load_lds(
                (const __attribute__((address_space(1))) void*)g,
                (__attribute__((address_space(3))) void*)&lds4[s],
                16, 0, 0);
        }
    }
    __syncthreads();   // drains vmcnt -> all LDS writes landed

    // pool: one iteration = one bin x channel-pair (ch0, ch0+8)
    for (int o = tid; o < NBINS * HCH; o += 256) {
        const int ch0 = o / NBINS;              // 0..7
        const int bin = o - ch0 * NBINS;
        const int px  = bin % POOL_P;
        const int py  = bin / POOL_P;

        // AdaptiveMaxPool2d: start=floor(i*h/P), end=ceil((i+1)*h/P)
        // non-negative operands -> C division == floor; ceil via (a+P-1)/P
        const int ys = y1 + (py * h) / POOL_P;
        const int ye = y1 + ((py + 1) * h + POOL_P - 1) / POOL_P;
        const int xs = x1 + (px * w) / POOL_P;
        const int xe = x1 + ((px + 1) * w + POOL_P - 1) / POOL_P;

        float m0 = -FLT_MAX, m1 = -FLT_MAX;     // empty bin -> finfo(f32).min
        if (fast) {
            // lds float index: (y-y1)*324 + ch*20 + (x-xa)
            const int base = ch0 * MAXW - y1 * ROWFL - xa;
            for (int y = ys; y < ye; ++y) {
                const int rowb = base + y * ROWFL;
                for (int x = xs; x < xe; ++x) {
                    m0 = fmaxf(m0, lds[rowb + x]);
                    m1 = fmaxf(m1, lds[rowb + HCH * MAXW + x]);   // +160: 2-way, free
                }
            }
        } else {
            // crop too big for LDS tile -> direct global pooling
            const float* f0 = fb + (size_t)ch0 * HWs;
            const float* f1 = f0 + (size_t)HCH * HWs;
            for (int y = ys; y < ye; ++y)
                for (int x = xs; x < xe; ++x) {
                    m0 = fmaxf(m0, f0[(size_t)y * W + x]);
                    m1 = fmaxf(m1, f1[(size_t)y * W + x]);
                }
        }
        const size_t ob = ((size_t)n * C + slab * SLAB + ch0) * NBINS + bin;
        out[ob] = m0;
        out[ob + (size_t)HCH * NBINS] = m1;
    }
}

extern "C" void kernel_launch(void* const* d_in, const int* in_sizes, int n_in,
                              void* d_out, int out_size, void* d_ws, size_t ws_size,
                              hipStream_t stream) {
    const float* features = (const float*)d_in[0];   // [B, C, H, W]
    const float* rois     = (const float*)d_in[1];   // [N, 5]
    float* out            = (float*)d_out;           // [N, C, 7, 7]

    const int C = 128, H = 64, W = 64;
    const int N = in_sizes[1] / 5;                   // 256

    const int grid = N * (C / SLAB);                 // 2048
    roipool_kernel<<<grid, 256, 0, stream>>>(features, rois, out, C, H, W, N);
}

// Round 15
// 64.265 us; speedup vs baseline: 1.0652x; 1.0246x over previous
//
#include <hip/hip_runtime.h>
#include <float.h>

// RoIPool (torch semantics: round(coords*scale), clamp, AdaptiveMaxPool2d bins)
// features: [B=4, C=128, H=64, W=64] fp32; rois: [N,5]; out: [N,128,7,7] fp32
//
// R15 change: SLAB 16 -> 8, grid 2048 -> 4096. Work accounting says throughput
// phases sum ~3us/CU but kernel ~15-18us -> latency/serialization bound. Halve
// per-block serial depth (staging 1.7 iters/thread, pool <=1 iter), LDS 11.2KB
// -> all 8 blocks/CU resident (wave-limited, not LDS-limited) -> deeper
// cross-block overlap of staging latency windows.
//
// Carries: global_load_lds DMA staging (R14), dynamic tap loops + channel-pair
// (R13), bank-rotating row stride (R11: 41 f4 = 164 fl = 4 mod 32), needed-seg
// trim (R12). Adaptive bin <= h/P+2 <= 4 for h<=17 (R4/R6 bug: assumed 3).
// Wave-uniform-LDS-base rule (m104): interior lanes stay ACTIVE with clamped
// duplicate addresses; only loop-tail is exec-masked (suffix -> lane0 active).

#define POOL_P 7
#define NBINS  49
#define SPATIAL_SCALE 0.0625f
#define SLAB   8                    // channels per block (C/SLAB = 16 slabs)
#define MAXH   17                   // max crop rows in LDS tile
#define MAXW   20                   // col span: min(x1&~3, 44) .. +19 covers x1..x2
#define SEGS   (MAXW / 4)           // 5 float4 segments per (row,ch)
#define ROWF4  (SLAB * SEGS + 1)    // 41 f4 per row (pad -> 164 fl = 4 mod 32)
#define ROWFL  (ROWF4 * 4)          // 164 floats per row
#define HCH    (SLAB / 2)           // 4: channel-pair stride

__global__ __launch_bounds__(256) void roipool_kernel(
    const float* __restrict__ feat,
    const float* __restrict__ rois,
    float* __restrict__ out,
    int C, int H, int W, int N)
{
    __shared__ float4 lds4[MAXH * ROWF4];       // 697 f4 = 11152 B -> 8 blk/CU
    const float* lds = (const float*)lds4;

    const int bid  = blockIdx.x;
    const int slab = bid & 15;                  // 16 slabs of 8 channels
    const int n    = bid >> 4;
    const int tid  = threadIdx.x;

    // ROI decode (block-uniform)
    const float* r = rois + (size_t)n * 5;
    const int b  = (int)r[0];                                  // astype(int32) = trunc
    int x1 = max(__float2int_rn(r[1] * SPATIAL_SCALE), 0);     // jnp.round = half-to-even
    int y1 = max(__float2int_rn(r[2] * SPATIAL_SCALE), 0);
    int x2 = min(__float2int_rn(r[3] * SPATIAL_SCALE), W - 1);
    int y2 = min(__float2int_rn(r[4] * SPATIAL_SCALE), H - 1);

    const int h = y2 - y1 + 1;                  // 1..17 for this generator
    const int w = x2 - x1 + 1;
    const int xa = min(x1 & ~3, W - MAXW);      // aligned; xa+19 <= W-1; x2-xa <= 19

    const size_t HWs = (size_t)H * W;
    const float* fb  = feat + ((size_t)b * C + slab * SLAB) * HWs;

    const bool fast = (h <= MAXH) && (w <= MAXW - 3);

    if (fast) {
        const int sa = (x1 - xa) >> 2;          // first needed segment
        const int se = (x2 - xa) >> 2;          // last needed segment (incl)
        const int hf4 = h * ROWF4;              // <= 697; avg ~435
        for (int s = tid; s < hf4; s += 256) {
            const int row  = s / ROWF4;         // const divisors only
            const int rowc = min(row, h - 1);   // masked-tail lanes: valid addr
            int rem = s - row * ROWF4;
            if (rem >= SLAB * SEGS) rem = SLAB * SEGS - 1;   // pad slot -> dup
            int ch  = rem / SEGS;
            int seg = rem - ch * SEGS;
            seg = min(max(seg, sa), se);        // trimmed segs -> dup (never read)
            const float* g = fb + (size_t)ch * HWs
                                + (size_t)(y1 + rowc) * W + xa + seg * 4;
            __builtin_amdgcn_global_load_lds(
                (const __attribute__((address_space(1))) void*)g,
                (__attribute__((address_space(3))) void*)&lds4[s],
                16, 0, 0);
        }
    }
    __syncthreads();   // drains vmcnt -> all LDS writes landed

    // pool: one iteration = one bin x channel-pair (ch0, ch0+4); 196 iters
    for (int o = tid; o < NBINS * HCH; o += 256) {
        const int ch0 = o / NBINS;              // 0..3
        const int bin = o - ch0 * NBINS;
        const int px  = bin % POOL_P;
        const int py  = bin / POOL_P;

        // AdaptiveMaxPool2d: start=floor(i*h/P), end=ceil((i+1)*h/P)
        // non-negative operands -> C division == floor; ceil via (a+P-1)/P
        const int ys = y1 + (py * h) / POOL_P;
        const int ye = y1 + ((py + 1) * h + POOL_P - 1) / POOL_P;
        const int xs = x1 + (px * w) / POOL_P;
        const int xe = x1 + ((px + 1) * w + POOL_P - 1) / POOL_P;

        float m0 = -FLT_MAX, m1 = -FLT_MAX;     // empty bin -> finfo(f32).min
        if (fast) {
            // lds float index: (y-y1)*164 + ch*20 + (x-xa)
            const int base = ch0 * MAXW - y1 * ROWFL - xa;
            for (int y = ys; y < ye; ++y) {
                const int rowb = base + y * ROWFL;
                for (int x = xs; x < xe; ++x) {
                    m0 = fmaxf(m0, lds[rowb + x]);
                    m1 = fmaxf(m1, lds[rowb + HCH * MAXW + x]);   // +80 fl
                }
            }
        } else {
            // crop too big for LDS tile -> direct global pooling
            const float* f0 = fb + (size_t)ch0 * HWs;
            const float* f1 = f0 + (size_t)HCH * HWs;
            for (int y = ys; y < ye; ++y)
                for (int x = xs; x < xe; ++x) {
                    m0 = fmaxf(m0, f0[(size_t)y * W + x]);
                    m1 = fmaxf(m1, f1[(size_t)y * W + x]);
                }
        }
        const size_t ob = ((size_t)n * C + slab * SLAB + ch0) * NBINS + bin;
        out[ob] = m0;
        out[ob + (size_t)HCH * NBINS] = m1;
    }
}

extern "C" void kernel_launch(void* const* d_in, const int* in_sizes, int n_in,
                              void* d_out, int out_size, void* d_ws, size_t ws_size,
                              hipStream_t stream) {
    const float* features = (const float*)d_in[0];   // [B, C, H, W]
    const float* rois     = (const float*)d_in[1];   // [N, 5]
    float* out            = (float*)d_out;           // [N, C, 7, 7]

    const int C = 128, H = 64, W = 64;
    const int N = in_sizes[1] / 5;                   // 256

    const int grid = N * (C / SLAB);                 // 4096
    roipool_kernel<<<grid, 256, 0, stream>>>(features, rois, out, C, H, W, N);
}